// Round 13
// baseline (49.619 us; speedup 1.0000x reference)
//
#include <hip/hip_runtime.h>
#include <hip/hip_bf16.h>

#define HW        1659      // 21*79
#define GLYPH_DIM 1536

typedef _Float16 half8  __attribute__((ext_vector_type(8)));
typedef _Float16 half2v __attribute__((ext_vector_type(2)));
typedef float    f32x4  __attribute__((ext_vector_type(4)));
typedef int      int4v  __attribute__((ext_vector_type(4)));

__device__ __forceinline__ unsigned int pk(float a, float b) {
    return __builtin_bit_cast(unsigned int, __builtin_amdgcn_cvt_pkrtz(a, b));
}

__device__ __forceinline__ half8 h8u(unsigned int a, unsigned int b,
                                     unsigned int c, unsigned int d) {
    uint4 u = make_uint4(a, b, c, d);
    return __builtin_bit_cast(half8, u);
}

// f32 Pade(5,4) tanh: x(945+105y+y^2)/(945+420y+15y^2); clamp in +-4, out +-1.
__device__ __forceinline__ float tanh_pade(float x) {
    float xc = fmaxf(fminf(x, 4.0f), -4.0f);
    float y  = xc * xc;
    float num = xc * fmaf(y, y + 105.0f, 945.0f);
    float den = fmaf(y, fmaf(y, 15.0f, 420.0f), 945.0f);
    float r = num * __builtin_amdgcn_rcpf(den);
    return fmaxf(fminf(r, 1.0f), -1.0f);
}

// ---------------- K1: histogram -> sorted unique ids + lens ----------------
__global__ __launch_bounds__(256, 8) void k1_histo(
    const int* __restrict__ gchar, const int* __restrict__ gcol,
    unsigned short* __restrict__ ids_bt,    // [B][64]
    unsigned short* __restrict__ ids_tb16,  // [B/16][64 t][16 b-in-group]
    int* __restrict__ lens_g)
{
    __shared__ unsigned int   mask[4][48];
    __shared__ unsigned short ids_s[4][64];

    const int tid = threadIdx.x;
    const int b0  = blockIdx.x * 4;

    if (tid < 192) ((unsigned int*)mask)[tid] = 0u;
    __syncthreads();

    const int4v* cp = (const int4v*)(gchar + (long)b0 * HW);
    const int4v* kp = (const int4v*)(gcol  + (long)b0 * HW);
    const int n4 = HW;   // 1659 int4s over this block's 4 batches

    // 2-deep pairing: 4 int4 loads in flight per thread before first use
    for (int idx = tid; idx < n4; idx += 512) {
        int  idxB = idx + 256;
        bool vB   = idxB < n4;
        int4v cA = __builtin_nontemporal_load(&cp[idx]);
        int4v kA = __builtin_nontemporal_load(&kp[idx]);
        int4v cB = {}, kB = {};
        if (vB) {
            cB = __builtin_nontemporal_load(&cp[idxB]);
            kB = __builtin_nontemporal_load(&kp[idxB]);
        }
        {
            int gg  = idx * 4;
            int bl0 = gg / HW;
            int rem = gg - bl0 * HW;
            int bl1 = bl0 + ((rem + 1) >= HW);
            int bl2 = bl0 + ((rem + 2) >= HW);
            int bl3 = bl0 + ((rem + 3) >= HW);
            int id0 = cA[0] * 16 + kA[0];
            int id1 = cA[1] * 16 + kA[1];
            int id2 = cA[2] * 16 + kA[2];
            int id3 = cA[3] * 16 + kA[3];
            atomicOr(&mask[bl0][id0 >> 5], 1u << (id0 & 31));
            atomicOr(&mask[bl1][id1 >> 5], 1u << (id1 & 31));
            atomicOr(&mask[bl2][id2 >> 5], 1u << (id2 & 31));
            atomicOr(&mask[bl3][id3 >> 5], 1u << (id3 & 31));
        }
        if (vB) {
            int gg  = idxB * 4;
            int bl0 = gg / HW;
            int rem = gg - bl0 * HW;
            int bl1 = bl0 + ((rem + 1) >= HW);
            int bl2 = bl0 + ((rem + 2) >= HW);
            int bl3 = bl0 + ((rem + 3) >= HW);
            int id0 = cB[0] * 16 + kB[0];
            int id1 = cB[1] * 16 + kB[1];
            int id2 = cB[2] * 16 + kB[2];
            int id3 = cB[3] * 16 + kB[3];
            atomicOr(&mask[bl0][id0 >> 5], 1u << (id0 & 31));
            atomicOr(&mask[bl1][id1 >> 5], 1u << (id1 & 31));
            atomicOr(&mask[bl2][id2 >> 5], 1u << (id2 & 31));
            atomicOr(&mask[bl3][id3 >> 5], 1u << (id3 & 31));
        }
    }
    __syncthreads();

    if (tid < 128) {
        const int bl  = tid >> 5;
        const int l32 = tid & 31;
        unsigned long long m = 0ull;
        if (l32 < 24)
            m = ((unsigned long long)mask[bl][2 * l32 + 1] << 32) |
                (unsigned long long)mask[bl][2 * l32];
        int cnt  = __popcll(m);
        int incl = cnt;
        #pragma unroll
        for (int d = 1; d < 32; d <<= 1) {
            int nb = __shfl_up(incl, d, 32);
            if (l32 >= d) incl += nb;
        }
        int excl  = incl - cnt;
        int total = __shfl(incl, 31, 32);
        if (l32 == 0) lens_g[b0 + bl] = min(total, 64);
        ids_s[bl][l32]      = GLYPH_DIM;
        ids_s[bl][l32 + 32] = GLYPH_DIM;
        unsigned long long mm = m;
        int r = excl;
        while (mm != 0ull && r < 64) {
            int bit = __builtin_ctzll(mm);
            ids_s[bl][r] = (unsigned short)(l32 * 64 + bit);
            ++r;
            mm &= (mm - 1ull);
        }
    }
    __syncthreads();

    if (tid < 128)
        ((unsigned int*)(ids_bt + (long)b0 * 64))[tid] = ((unsigned int*)ids_s)[tid];
    {
        const int bl = tid >> 6, t = tid & 63;
        const int b  = b0 + bl;
        ids_tb16[((long)(b >> 4) * 64 + t) * 16 + (b & 15)] = ids_s[bl][t];
    }
}

// ---------------- K2: emb/bag only, fully coalesced ----------------
// Block = 8 batches. emb float4 #i: row=i/5, part=i%5 -> address base+i*16.
__global__ __launch_bounds__(256, 8) void k2_emb(
    const float* __restrict__ ctab, const float* __restrict__ ktab,
    const unsigned short* __restrict__ ids_bt,
    float* __restrict__ out_emb, float* __restrict__ out_bag)
{
    __shared__ float          tabs[1620];
    __shared__ unsigned short ids_l[512];

    const int tid = threadIdx.x;
    const long r0 = (long)blockIdx.x * 512;   // first row of this block

    for (int i = tid; i < 1620; i += 256)
        tabs[i] = (i < 1552) ? ctab[i] : ktab[i - 1552];
    ((unsigned int*)ids_l)[tid] = ((const unsigned int*)(ids_bt + r0))[tid];
    __syncthreads();

    // emb: 512 rows * 5 f32x4 = 2560 f32x4, 10 per thread
    float* eb = out_emb + r0 * 20;
    #pragma unroll
    for (int j = 0; j < 10; ++j) {
        int i    = tid + j * 256;
        int row  = i / 5;
        int part = i - row * 5;
        int id = ids_l[row];
        int ch = id >> 4;
        int co = (id >= GLYPH_DIM) ? 16 : (id & 15);
        int off = (part < 4) ? (ch * 16 + part * 4) : (1552 + co * 4);
        *(f32x4*)(eb + (long)i * 4) = *(const f32x4*)&tabs[off];
    }
    // bag: 512 rows * 2 f32 = 1024 f32 = 256 f32x4, 1 per thread (2 rows)
    {
        int id0 = ids_l[2 * tid];
        int id1 = ids_l[2 * tid + 1];
        f32x4 v;
        v[0] = (float)(id0 >> 4);
        v[1] = (float)((id0 >= GLYPH_DIM) ? 16 : (id0 & 15));
        v[2] = (float)(id1 >> 4);
        v[3] = (float)((id1 >= GLYPH_DIM) ? 16 : (id1 & 15));
        *(f32x4*)(out_bag + r0 * 2 + tid * 4) = v;
    }
}

// ---------------- K3: RNN only. 256 blocks x 1 wave = 1 chain of 16 batches.
// tau(g,j) = {4g..4g+3, 16+4g..19+4g} on A and B; C/D layout (col=lane&15
// =batch, row=(lane>>4)*4+reg) IS next step's B-fragment. x/P prefetched.
__global__ __launch_bounds__(64, 1) void k3_rnn(
    const float* __restrict__ ctab, const float* __restrict__ ktab,
    const float* __restrict__ Wih, const float* __restrict__ Whh,
    const float* __restrict__ bih, const float* __restrict__ bhh,
    const unsigned short* __restrict__ ids_tb16,
    const int* __restrict__ lens_g,
    float* __restrict__ out_h)
{
    __shared__ _Float16       tabsh[1664];    // f16 tables
    __shared__ unsigned short ids_l[1024];    // [64 t][16 n]

    const int l = threadIdx.x;
    const int n = l & 15, g = l >> 4;
    const int bg = blockIdx.x;                // 16-batch group

    // stage tables (f16) + ids
    for (int i = l; i < 1552; i += 64) tabsh[i] = (_Float16)ctab[i];
    if (l < 68) tabsh[1552 + l] = (_Float16)ktab[l];
    {
        const unsigned int* src = (const unsigned int*)(ids_tb16 + (long)bg * 1024);
        unsigned int* dst = (unsigned int*)ids_l;
        #pragma unroll
        for (int j = 0; j < 8; ++j) dst[l + j * 64] = src[l + j * 64];
    }

    half8 wihA0, wihA1, whhA0, whhA1;
    f32x4 bias0, bias1;
    #pragma unroll
    for (int j = 0; j < 8; ++j) {
        int kk = (j < 4) ? (4 * g + j) : (12 + 4 * g + j);   // tau(g,j)
        wihA0[j] = (_Float16)((kk < 20) ? Wih[n * 20 + kk] : 0.0f);
        wihA1[j] = (_Float16)((kk < 20) ? Wih[(n + 16) * 20 + kk] : 0.0f);
        whhA0[j] = (_Float16)Whh[n * 32 + kk];
        whhA1[j] = (_Float16)Whh[(n + 16) * 32 + kk];
    }
    #pragma unroll
    for (int i = 0; i < 4; ++i) {
        bias0[i] = bih[4 * g + i] + bhh[4 * g + i];
        bias1[i] = bih[16 + 4 * g + i] + bhh[16 + 4 * g + i];
    }
    const int len = lens_g[bg * 16 + n];
    __syncthreads();

    auto build = [&](int id) -> half8 {
        int ch = id >> 4;
        int co = (id >= GLYPH_DIM) ? 16 : (id & 15);
        uint2 c8 = *(const uint2*)&tabsh[ch * 16 + 4 * g];
        uint2 k8 = make_uint2(0u, 0u);
        if (g == 0) k8 = *(const uint2*)&tabsh[1552 + co * 4];
        return h8u(c8.x, c8.y, k8.x, k8.y);
    };

    half8 x0  = build(ids_l[n]);
    f32x4 Pc0 = __builtin_amdgcn_mfma_f32_16x16x32_f16(wihA0, x0, bias0, 0, 0, 0);
    f32x4 Pc1 = __builtin_amdgcn_mfma_f32_16x16x32_f16(wihA1, x0, bias1, 0, 0, 0);
    int idn = ids_l[16 + n];
    unsigned int hw0 = 0u, hw1 = 0u, hw2 = 0u, hw3 = 0u;

    for (int t = 0; t < 64; ++t) {
        // off-chain: x_{t+1} gather + next-id read issued first
        half8 xn   = build(idn);
        int   idn2 = ids_l[((t < 62) ? t + 2 : 63) * 16 + n];

        // serial chain: pack(h) -> 2 MFMA -> 8 tanh -> select
        half8 hB = h8u(hw0, hw1, hw2, hw3);
        f32x4 a0 = __builtin_amdgcn_mfma_f32_16x16x32_f16(whhA0, hB, Pc0, 0, 0, 0);
        f32x4 a1 = __builtin_amdgcn_mfma_f32_16x16x32_f16(whhA1, hB, Pc1, 0, 0, 0);
        unsigned int t0 = pk(tanh_pade(a0[0]), tanh_pade(a0[1]));
        unsigned int t1 = pk(tanh_pade(a0[2]), tanh_pade(a0[3]));
        unsigned int t2 = pk(tanh_pade(a1[0]), tanh_pade(a1[1]));
        unsigned int t3 = pk(tanh_pade(a1[2]), tanh_pade(a1[3]));
        bool upd = (t < len);
        hw0 = upd ? t0 : hw0;
        hw1 = upd ? t1 : hw1;
        hw2 = upd ? t2 : hw2;
        hw3 = upd ? t3 : hw3;

        // off-chain: P_{t+1}
        Pc0 = __builtin_amdgcn_mfma_f32_16x16x32_f16(wihA0, xn, bias0, 0, 0, 0);
        Pc1 = __builtin_amdgcn_mfma_f32_16x16x32_f16(wihA1, xn, bias1, 0, 0, 0);
        idn = idn2;
    }

    half2v u0 = __builtin_bit_cast(half2v, hw0);
    half2v u1 = __builtin_bit_cast(half2v, hw1);
    half2v u2 = __builtin_bit_cast(half2v, hw2);
    half2v u3 = __builtin_bit_cast(half2v, hw3);
    f32x4 o0 = {(float)u0[0], (float)u0[1], (float)u1[0], (float)u1[1]};
    f32x4 o1 = {(float)u2[0], (float)u2[1], (float)u3[0], (float)u3[1]};
    float* op = out_h + (long)(bg * 16 + n) * 32;
    *(f32x4*)(op + 4 * g)      = o0;
    *(f32x4*)(op + 16 + 4 * g) = o1;
}

extern "C" void kernel_launch(void* const* d_in, const int* in_sizes, int n_in,
                              void* d_out, int out_size, void* d_ws, size_t ws_size,
                              hipStream_t stream) {
    const int* gchar = (const int*)d_in[0];
    const int* gcol  = (const int*)d_in[1];
    const float* ctab = (const float*)d_in[2];
    const float* ktab = (const float*)d_in[3];
    const float* Wih  = (const float*)d_in[4];
    const float* Whh  = (const float*)d_in[5];
    const float* bih  = (const float*)d_in[6];
    const float* bhh  = (const float*)d_in[7];

    const int B = in_sizes[0] / HW;          // 4096
    float* out_h   = (float*)d_out;                    // B*32
    float* out_emb = out_h + (long)B * 32;             // B*64*20
    float* out_bag = out_emb + (long)B * 64 * 20;      // B*64*2

    unsigned short* ids_bt   = (unsigned short*)d_ws;                 // B*64 u16
    unsigned short* ids_tb16 = ids_bt + (long)B * 64;                 // B*64 u16
    int*            lens_g   = (int*)((char*)d_ws + (long)B * 64 * 4);// B ints

    k1_histo<<<B / 4, 256, 0, stream>>>(gchar, gcol, ids_bt, ids_tb16, lens_g);
    k2_emb<<<(B * 64) / 512, 256, 0, stream>>>(ctab, ktab, ids_bt, out_emb, out_bag);
    k3_rnn<<<B / 16, 64, 0, stream>>>(ctab, ktab, Wih, Whh, bih, bhh,
                                      ids_tb16, lens_g, out_h);
}